// Round 7
// baseline (1266.580 us; speedup 1.0000x reference)
//
#include <hip/hip_runtime.h>
#include <math.h>

#define B 16
#define S 512
#define IN 64
#define D 512
#define H 8
#define DK 64
#define L 6
#define F 2048
#define BS (B*S)          /* 8192 */
#define EPS 1e-5f

typedef short short8 __attribute__((ext_vector_type(8)));
typedef short short4v __attribute__((ext_vector_type(4)));
typedef float floatx4 __attribute__((ext_vector_type(4)));

static __device__ inline short f2bf(float x) {
    unsigned u = __float_as_uint(x);
    unsigned r = (u + 0x7fffu + ((u >> 16) & 1u)) >> 16;
    return (short)r;
}
static __device__ inline float bf2f(short s) {
    return __uint_as_float(((unsigned)(unsigned short)s) << 16);
}

// ---------------------------------------------------------------------------
// pe[k][d] = (1/S) * sum_q rel_emb[clip(q-k,-32,32)+32][d]   (closed form)
// ---------------------------------------------------------------------------
__global__ __launch_bounds__(256) void pe_kernel(const float* __restrict__ rel_emb,
                                                 float* __restrict__ pe) {
    int k = blockIdx.x;
    int d = threadIdx.x;
    float acc0 = 0.f, acc1 = 0.f;
    for (int r = 0; r < 65; ++r) {
        float w;
        if (r == 0)       w = (float)max(0, k - 31);
        else if (r == 64) w = (float)max(0, S - (k + 32));
        else {
            int qpos = k + r - 32;
            w = (qpos >= 0 && qpos < S) ? 1.f : 0.f;
        }
        acc0 += w * rel_emb[r * D + d];
        acc1 += w * rel_emb[r * D + d + 256];
    }
    pe[k * D + d]       = acc0 * (1.f / (float)S);
    pe[k * D + d + 256] = acc1 * (1.f / (float)S);
}

// ---------------------------------------------------------------------------
// Weight transpose + bf16 convert: src (z,K,N) f32 -> dst (z,N,K) bf16
// ---------------------------------------------------------------------------
__global__ __launch_bounds__(256) void wtrans_kernel(const float* __restrict__ src,
                                                     short* __restrict__ dst,
                                                     int K, int N) {
    __shared__ float Ls[32][33];
    const int z = blockIdx.z, kb = blockIdx.y, nb = blockIdx.x;
    const int tx = threadIdx.x & 31, ty = threadIdx.x >> 5;
    src += (size_t)z * K * N;
    dst += (size_t)z * K * N;
#pragma unroll
    for (int i = 0; i < 4; ++i)
        Ls[ty + i * 8][tx] = src[(size_t)(kb * 32 + ty + i * 8) * N + nb * 32 + tx];
    __syncthreads();
#pragma unroll
    for (int i = 0; i < 4; ++i) {
        int n = nb * 32 + ty + i * 8;
        dst[(size_t)n * K + kb * 32 + tx] = f2bf(Ls[tx][ty + i * 8]);
    }
}

// elementwise f32 -> bf16
__global__ __launch_bounds__(256) void cvt_kernel(const float* __restrict__ in,
                                                  short* __restrict__ out) {
    int i = (blockIdx.x * 256 + threadIdx.x) * 4;
    float4 v = *(const float4*)(in + i);
    short4v o;
    o.x = f2bf(v.x); o.y = f2bf(v.y); o.z = f2bf(v.z); o.w = f2bf(v.w);
    *(short4v*)(out + i) = o;
}

// ---------------------------------------------------------------------------
// V transpose per (b,h): v (BH,S,DK) bf16 -> vt (BH,DK,S) bf16, 64x64 tiles
// ---------------------------------------------------------------------------
__global__ __launch_bounds__(256) void vtrans_kernel(const short* __restrict__ v,
                                                     short* __restrict__ vt) {
    __shared__ short Ls[64 * 72];
    const int bh = blockIdx.y, jt = blockIdx.x * 64;
    const int t = threadIdx.x;
    const int r = t >> 2, cg = t & 3;
    *(short8*)&Ls[r * 72 + cg * 8] =
        *(const short8*)(v + ((size_t)bh * S + jt + r) * DK + cg * 8);
    *(short8*)&Ls[r * 72 + 32 + cg * 8] =
        *(const short8*)(v + ((size_t)bh * S + jt + r) * DK + 32 + cg * 8);
    __syncthreads();
    const int d = t >> 2, sg = t & 3;
    short tmp[16];
#pragma unroll
    for (int i = 0; i < 16; ++i) tmp[i] = Ls[(sg * 16 + i) * 72 + d];
    short* dst = vt + ((size_t)bh * DK + d) * S + jt + sg * 16;
    *(short8*)(dst)     = *(short8*)&tmp[0];
    *(short8*)(dst + 8) = *(short8*)&tmp[8];
}

// ---------------------------------------------------------------------------
// bf16 MFMA GEMM with 3-stage vmcnt-gated K-loop (AITER-style: loads stay in
// flight across barriers; never vmcnt(0) mid-loop). Three statically distinct
// LDS buffers so the backend cannot conservatively insert extra waits.
// C = A(M,K) @ Bt(N,K)^T [+ bias]; 128x128 tile, BK=32, 256 thr, 4x4 MFMA/wave.
// mode 0: Cb=bf16(v+bias)  1: +relu  2: +pe[row%S][col]
// mode 3: Cb[z] scatter to (B,H,S,DK)   mode 4: Cf = v (f32 partial, no bias)
// ---------------------------------------------------------------------------
#define GLL(SRC, DST) __builtin_amdgcn_global_load_lds( \
    (const __attribute__((address_space(1))) void*)(SRC), \
    (__attribute__((address_space(3))) void*)(DST), 16, 0, 0)

// s_waitcnt imm: lgkmcnt=15 (no wait) | expcnt=7 (no wait) | vmcnt low bits
#define SWAIT4 __builtin_amdgcn_s_waitcnt(0x0F74)   /* wait until <=4 vmem */
#define SWAIT0 __builtin_amdgcn_s_waitcnt(0x0F70)   /* wait until 0 vmem  */

#define KITER(CUR_A, CUR_B, NXT_A, NXT_B, I)                              \
  {                                                                       \
    if ((I) + 1 < niter) SWAIT4; else SWAIT0;                             \
    __builtin_amdgcn_s_barrier();                                         \
    const int kn_ = ((I) + 2) << 5;                                       \
    if (kn_ < K) {                                                        \
      GLL(Ag0 + kn_, NXT_A + so0); GLL(Ag1 + kn_, NXT_A + so1);           \
      GLL(Bg0 + kn_, NXT_B + so0); GLL(Bg1 + kn_, NXT_B + so1);           \
    }                                                                     \
    short8 af_[4], bf_[4];                                                \
    _Pragma("unroll")                                                     \
    for (int mt = 0; mt < 4; ++mt) {                                      \
      af_[mt] = *(const short8*)&CUR_A[((wm * 4 + mt) * 64 + slot) * 8];  \
      bf_[mt] = *(const short8*)&CUR_B[((wn * 4 + mt) * 64 + slot) * 8];  \
    }                                                                     \
    _Pragma("unroll")                                                     \
    for (int mt = 0; mt < 4; ++mt)                                        \
      _Pragma("unroll")                                                   \
      for (int nt = 0; nt < 4; ++nt)                                      \
        acc[mt][nt] = __builtin_amdgcn_mfma_f32_16x16x32_bf16(            \
            af_[mt], bf_[nt], acc[mt][nt], 0, 0, 0);                      \
  }

__global__ __launch_bounds__(256) void mfma_gemm(
    const short* __restrict__ A, const short* __restrict__ Bt,
    const float* __restrict__ bias, short* __restrict__ Cb,
    float* __restrict__ Cf, int M, int N, int K, int lda, int ldb, int mode,
    const float* __restrict__ pe, long az, long wz, long bz, long cz)
{
    __shared__ short As0[4096], As1[4096], As2[4096];
    __shared__ short Bs0[4096], Bs1[4096], Bs2[4096];

    const int z = blockIdx.z;
    const short* Az = A  + (size_t)z * az;
    const short* Bz = Bt + (size_t)z * wz;

    const int t = threadIdx.x;
    const int w = t >> 6, lane = t & 63;
    const int wm = w >> 1, wn = w & 1;
    const int ln15 = lane & 15, lq = lane >> 4;
    const int bm = blockIdx.y, bn = blockIdx.x;

    // staging lane mapping (inverse of the XOR granule swizzle)
    const int ml = lane >> 2;
    const int kb = ((lane & 3) - (ml >> 1)) & 3;
    const short* Ag0 = Az + (size_t)(bm * 128 + w * 16 + ml)       * lda + kb * 8;
    const short* Ag1 = Az + (size_t)(bm * 128 + (w + 4) * 16 + ml) * lda + kb * 8;
    const short* Bg0 = Bz + (size_t)(bn * 128 + w * 16 + ml)       * ldb + kb * 8;
    const short* Bg1 = Bz + (size_t)(bn * 128 + (w + 4) * 16 + ml) * ldb + kb * 8;
    const int so0 = w * 512, so1 = (w + 4) * 512;

    floatx4 acc[4][4] = {};
    const int slot = ln15 * 4 + ((lq + (ln15 >> 1)) & 3);
    const int niter = K >> 5;

    // prologue: stage buffers 0 and 1 (groups of 4 vmem ops per wave)
    GLL(Ag0, As0 + so0); GLL(Ag1, As0 + so1);
    GLL(Bg0, Bs0 + so0); GLL(Bg1, Bs0 + so1);
    if (niter > 1) {
        GLL(Ag0 + 32, As1 + so0); GLL(Ag1 + 32, As1 + so1);
        GLL(Bg0 + 32, Bs1 + so0); GLL(Bg1 + 32, Bs1 + so1);
    }

    int i = 0;
    for (; i + 3 <= niter; i += 3) {
        KITER(As0, Bs0, As2, Bs2, i);
        KITER(As1, Bs1, As0, Bs0, i + 1);
        KITER(As2, Bs2, As1, Bs1, i + 2);
    }
    if (i < niter)     KITER(As0, Bs0, As2, Bs2, i);
    if (i + 1 < niter) KITER(As1, Bs1, As0, Bs0, i + 1);

    short* Cbz = Cb + (size_t)z * cz;
    float* Cfz = Cf + (size_t)z * cz;
    const float* bb = bias + (size_t)z * bz;
#pragma unroll
    for (int mt = 0; mt < 4; ++mt) {
#pragma unroll
        for (int nt = 0; nt < 4; ++nt) {
            const int col = bn * 128 + wn * 64 + nt * 16 + ln15;
            const int row0 = bm * 128 + wm * 64 + mt * 16 + lq * 4;
            const float bc = (mode == 4) ? 0.f : bb[col];
#pragma unroll
            for (int reg = 0; reg < 4; ++reg) {
                const int r = row0 + reg;
                float v = acc[mt][nt][reg] + bc;
                if (mode == 4) {
                    Cfz[(size_t)r * N + col] = v;
                } else if (mode == 3) {
                    const int bi = r >> 9, si = r & (S - 1);
                    const int hh = col >> 6, dd = col & 63;
                    Cbz[(((size_t)(bi * H + hh) * S + si) * DK + dd)] = f2bf(v);
                } else {
                    if (mode == 1) v = fmaxf(v, 0.f);
                    else if (mode == 2) v += pe[(size_t)(r & (S - 1)) * D + col];
                    Cb[(size_t)r * N + col] = f2bf(v);
                }
            }
        }
    }
}

// ---------------------------------------------------------------------------
// bf16 MFMA flash attention. grid (S/64, B*H), 256 thr = 4 waves x 16 q-rows.
// q,k: (BH,S,DK) bf16 ; vt: (BH,DK,S) bf16 ; ctx out: (B,S,D) bf16
// ---------------------------------------------------------------------------
__global__ __launch_bounds__(256) void attn_mfma(
    const short* __restrict__ qg, const short* __restrict__ kg,
    const short* __restrict__ vtg, short* __restrict__ ctx)
{
    __shared__ short Ks[64 * 72];      // [kv][d]
    __shared__ short Vs[64 * 72];      // [dv][kv]
    __shared__ short Ps[4][16 * 72];   // per-wave P [m][kv] (wave-private)

    const int t = threadIdx.x;
    const int w = t >> 6, lane = t & 63;
    const int ln15 = lane & 15, lq = lane >> 4;
    const int bh = blockIdx.y, bi = bh >> 3, hh = bh & 7;
    const int qbase = blockIdx.x * 64 + w * 16;

    short8 qf0, qf1;
    {
        const short* qrow = qg + ((size_t)bh * S + qbase + ln15) * DK;
        qf0 = *(const short8*)(qrow + lq * 8);
        qf1 = *(const short8*)(qrow + 32 + lq * 8);
    }
    floatx4 o[4] = {};
    float mrow[4] = {-1e30f, -1e30f, -1e30f, -1e30f};
    float lrow[4] = {};

    const int sr = t >> 2, scg = t & 3;
    const short* kbase = kg  + (size_t)bh * S * DK;
    const short* vtb   = vtg + (size_t)bh * DK * S;

    for (int jt = 0; jt < S; jt += 64) {
        __syncthreads();
        *(short8*)&Ks[sr * 72 + scg * 8] =
            *(const short8*)(kbase + (size_t)(jt + sr) * DK + scg * 8);
        *(short8*)&Ks[sr * 72 + 32 + scg * 8] =
            *(const short8*)(kbase + (size_t)(jt + sr) * DK + 32 + scg * 8);
        *(short8*)&Vs[sr * 72 + scg * 8] =
            *(const short8*)(vtb + (size_t)sr * S + jt + scg * 8);
        *(short8*)&Vs[sr * 72 + 32 + scg * 8] =
            *(const short8*)(vtb + (size_t)sr * S + jt + 32 + scg * 8);
        __syncthreads();

        floatx4 sc[4];
#pragma unroll
        for (int nt = 0; nt < 4; ++nt) {
            floatx4 s4 = {};
            short8 kf0 = *(const short8*)&Ks[(nt * 16 + ln15) * 72 + lq * 8];
            short8 kf1 = *(const short8*)&Ks[(nt * 16 + ln15) * 72 + 32 + lq * 8];
            s4 = __builtin_amdgcn_mfma_f32_16x16x32_bf16(qf0, kf0, s4, 0, 0, 0);
            s4 = __builtin_amdgcn_mfma_f32_16x16x32_bf16(qf1, kf1, s4, 0, 0, 0);
#pragma unroll
            for (int r = 0; r < 4; ++r) s4[r] *= 0.125f;
            sc[nt] = s4;
        }

        float rmax[4];
#pragma unroll
        for (int r = 0; r < 4; ++r)
            rmax[r] = fmaxf(fmaxf(sc[0][r], sc[1][r]), fmaxf(sc[2][r], sc[3][r]));
#pragma unroll
        for (int off = 1; off < 16; off <<= 1)
#pragma unroll
            for (int r = 0; r < 4; ++r)
                rmax[r] = fmaxf(rmax[r], __shfl_xor(rmax[r], off));

        float mnew[4], alpha[4], psum[4];
#pragma unroll
        for (int r = 0; r < 4; ++r) {
            mnew[r]  = fmaxf(mrow[r], rmax[r]);
            alpha[r] = __expf(mrow[r] - mnew[r]);
            psum[r]  = 0.f;
        }
#pragma unroll
        for (int nt = 0; nt < 4; ++nt)
#pragma unroll
            for (int r = 0; r < 4; ++r) {
                float p = __expf(sc[nt][r] - mnew[r]);
                psum[r] += p;
                Ps[w][(lq * 4 + r) * 72 + nt * 16 + ln15] = f2bf(p);
            }
#pragma unroll
        for (int off = 1; off < 16; off <<= 1)
#pragma unroll
            for (int r = 0; r < 4; ++r)
                psum[r] += __shfl_xor(psum[r], off);
#pragma unroll
        for (int r = 0; r < 4; ++r) {
            lrow[r] = lrow[r] * alpha[r] + psum[r];
            mrow[r] = mnew[r];
        }
#pragma unroll
        for (int dv = 0; dv < 4; ++dv)
#pragma unroll
            for (int r = 0; r < 4; ++r)
                o[dv][r] *= alpha[r];

        // no barrier: Ps[w] is wave-private; within-wave LDS order via lgkmcnt
        short8 pf0 = *(const short8*)&Ps[w][ln15 * 72 + lq * 8];
        short8 pf1 = *(const short8*)&Ps[w][ln15 * 72 + 32 + lq * 8];
#pragma unroll
        for (int dv = 0; dv < 4; ++dv) {
            short8 vf0 = *(const short8*)&Vs[(dv * 16 + ln15) * 72 + lq * 8];
            short8 vf1 = *(const short8*)&Vs[(dv * 16 + ln15) * 72 + 32 + lq * 8];
            o[dv] = __builtin_amdgcn_mfma_f32_16x16x32_bf16(pf0, vf0, o[dv], 0, 0, 0);
            o[dv] = __builtin_amdgcn_mfma_f32_16x16x32_bf16(pf1, vf1, o[dv], 0, 0, 0);
        }
    }

    float inv[4];
#pragma unroll
    for (int r = 0; r < 4; ++r) inv[r] = 1.f / lrow[r];
#pragma unroll
    for (int dv = 0; dv < 4; ++dv)
#pragma unroll
        for (int r = 0; r < 4; ++r) {
            const int s = qbase + lq * 4 + r;
            const int col = hh * DK + dv * 16 + ln15;
            ctx[((size_t)bi * S + s) * D + col] = f2bf(o[dv][r] * inv[r]);
        }
}

// ---------------------------------------------------------------------------
// Fused split-K combine + residual + LayerNorm:
//   x = bf2f(a) + p0 + p1 + eb[col] ; out = LN(x)*g + beta   (bf16 out)
// ---------------------------------------------------------------------------
__global__ __launch_bounds__(128) void ln_res_kernel(
    const short* __restrict__ a, const float* __restrict__ p0,
    const float* __restrict__ p1, const float* __restrict__ eb,
    const float* __restrict__ g, const float* __restrict__ beta,
    short* __restrict__ outb)
{
    const int row = blockIdx.x;
    const int t = threadIdx.x;
    const size_t off = (size_t)row * D + t * 4;
    const short4v xa = *(const short4v*)(a + off);
    const float4 q0 = *(const float4*)(p0 + off);
    const float4 q1 = *(const float4*)(p1 + off);
    const float4 bb2 = *(const float4*)(eb + t * 4);
    float x0 = bf2f(xa.x) + q0.x + q1.x + bb2.x;
    float x1 = bf2f(xa.y) + q0.y + q1.y + bb2.y;
    float x2 = bf2f(xa.z) + q0.z + q1.z + bb2.z;
    float x3 = bf2f(xa.w) + q0.w + q1.w + bb2.w;
    float s  = x0 + x1 + x2 + x3;
    float s2 = x0 * x0 + x1 * x1 + x2 * x2 + x3 * x3;
#pragma unroll
    for (int o = 32; o > 0; o >>= 1) {
        s  += __shfl_down(s, o);
        s2 += __shfl_down(s2, o);
    }
    __shared__ float red[2][2];
    const int wave = t >> 6;
    if ((t & 63) == 0) { red[wave][0] = s; red[wave][1] = s2; }
    __syncthreads();
    s  = red[0][0] + red[1][0];
    s2 = red[0][1] + red[1][1];
    const float mu  = s * (1.f / (float)D);
    const float var = s2 * (1.f / (float)D) - mu * mu;
    const float r   = rsqrtf(var + EPS);
    const float4 gg = *(const float4*)(g    + t * 4);
    const float4 bb = *(const float4*)(beta + t * 4);
    short4v ob;
    ob.x = f2bf((x0 - mu) * r * gg.x + bb.x);
    ob.y = f2bf((x1 - mu) * r * gg.y + bb.y);
    ob.z = f2bf((x2 - mu) * r * gg.z + bb.z);
    ob.w = f2bf((x3 - mu) * r * gg.w + bb.w);
    *(short4v*)(outb + off) = ob;
}

// ---------------------------------------------------------------------------
// out[row] = h[row,:] . out_W + out_b ; one wave per row (h is bf16)
// ---------------------------------------------------------------------------
__global__ __launch_bounds__(256) void out_kernel(
    const short* __restrict__ h, const float* __restrict__ ow,
    const float* __restrict__ ob, float* __restrict__ out)
{
    const int wave = threadIdx.x >> 6;
    const int lane = threadIdx.x & 63;
    const int row  = blockIdx.x * 4 + wave;
    const short* hp = h + (size_t)row * D;
    float s = 0.f;
#pragma unroll
    for (int u = 0; u < 8; ++u) {
        int d = lane + u * 64;
        s += bf2f(hp[d]) * ow[d];
    }
#pragma unroll
    for (int o = 32; o > 0; o >>= 1) s += __shfl_down(s, o);
    if (lane == 0) out[row] = s + ob[0];
}

// ---------------------------------------------------------------------------
extern "C" void kernel_launch(void* const* d_in, const int* in_sizes, int n_in,
                              void* d_out, int out_size, void* d_ws, size_t ws_size,
                              hipStream_t stream) {
    const float* x       = (const float*)d_in[0];
    const float* in_W    = (const float*)d_in[1];
    const float* in_b    = (const float*)d_in[2];
    const float* rel_emb = (const float*)d_in[3];
    const float* qkvo_W  = (const float*)d_in[4];
    const float* qkvo_b  = (const float*)d_in[5];
    const float* ln_g    = (const float*)d_in[6];
    const float* ln_bb   = (const float*)d_in[7];
    const float* ff_W1   = (const float*)d_in[8];
    const float* ff_b1   = (const float*)d_in[9];
    const float* ff_W2   = (const float*)d_in[10];
    const float* ff_b2   = (const float*)d_in[11];
    const float* out_W   = (const float*)d_in[12];
    const float* out_b   = (const float*)d_in[13];
    float* out = (float*)d_out;

    const size_t HSZ = (size_t)BS * D;              // 4.19M elems
    float* pe     = (float*)d_ws;                   // S*D f32
    float* part0  = pe + (size_t)S * D;             // BS*D f32 split-K partial
    float* part1  = part0 + HSZ;                    // BS*D f32
    short* h_bf   = (short*)(part1 + HSZ);
    short* h1_bf  = h_bf  + HSZ;
    short* qkv_bf = h1_bf + HSZ;                    // 4*HSZ: q,k,v,vt (ff1 alias)
    short* xb     = qkv_bf + 4 * HSZ;               // BS*IN
    short* wt_qkvo = xb + (size_t)BS * IN;          // L*4*D*D
    short* wt_ff1  = wt_qkvo + (size_t)L * 4 * D * D;  // L*D*F
    short* wt_ff2  = wt_ff1  + (size_t)L * D * F;      // L*F*D
    short* wt_in   = wt_ff2  + (size_t)L * F * D;      // D*IN

    const size_t CZ = (size_t)B * H * S * DK;       // == HSZ
    short* qb = qkv_bf;
    short* kb = qkv_bf + CZ;
    short* vb = qkv_bf + 2 * CZ;
    short* vt = qkv_bf + 3 * CZ;
    short* ctx_bf = vb;                             // alias (v dead after vtrans)
    short* ff1_bf = qkv_bf;                         // alias (qkv dead after Wo)

    dim3 blk(256);

    // --- prologue: pe, input cvt, ALL weight transposes (hoisted) ---
    pe_kernel<<<dim3(S), blk, 0, stream>>>(rel_emb, pe);
    cvt_kernel<<<dim3(BS * IN / 1024), blk, 0, stream>>>(x, xb);
    wtrans_kernel<<<dim3(D / 32, IN / 32, 1), blk, 0, stream>>>(in_W, wt_in, IN, D);
    wtrans_kernel<<<dim3(D / 32, D / 32, 4 * L), blk, 0, stream>>>(qkvo_W, wt_qkvo, D, D);
    wtrans_kernel<<<dim3(F / 32, D / 32, L), blk, 0, stream>>>(ff_W1, wt_ff1, D, F);
    wtrans_kernel<<<dim3(D / 32, F / 32, L), blk, 0, stream>>>(ff_W2, wt_ff2, F, D);

    // h = x @ in_W + in_b + pe   (bf16)
    mfma_gemm<<<dim3(D / 128, BS / 128, 1), blk, 0, stream>>>(
        xb, wt_in, in_b, h_bf, nullptr, BS, D, IN, IN, IN, 2, pe, 0, 0, 0, 0);

    for (int l = 0; l < L; ++l) {
        const float* bl = qkvo_b + (size_t)l * 4 * D;
        // q,k,v projections -> (B,H,S,DK) bf16  (z = which projection)
        mfma_gemm<<<dim3(D / 128, BS / 128, 3), blk, 0, stream>>>(
            h_bf, wt_qkvo + (size_t)l * 4 * D * D, bl, qkv_bf, nullptr,
            BS, D, D, D, D, 3, nullptr, 0, (long)D * D, (long)D, (long)CZ);
        vtrans_kernel<<<dim3(S / 64, B * H), blk, 0, stream>>>(vb, vt);
        attn_mfma<<<dim3(S / 64, B * H), blk, 0, stream>>>(qb, kb, vt, ctx_bf);
        // Wo: split-K=2 (K=512 -> 2x256), f32 partials (bias folded into LN)
        mfma_gemm<<<dim3(D / 128, BS / 128, 2), blk, 0, stream>>>(
            ctx_bf, wt_qkvo + (size_t)(l * 4 + 3) * D * D, nullptr, nullptr, part0,
            BS, D, 256, D, D, 4, nullptr, 256, 256, 0, (long)HSZ);
        // h1 = LN(h + p0 + p1 + b_o)
        ln_res_kernel<<<dim3(BS), dim3(128), 0, stream>>>(
            h_bf, part0, part1, bl + 3 * D,
            ln_g + (size_t)l * 2 * D, ln_bb + (size_t)l * 2 * D, h1_bf);
        // ff1 = relu(h1 @ W1 + b1)  (bf16)
        mfma_gemm<<<dim3(F / 128, BS / 128, 1), blk, 0, stream>>>(
            h1_bf, wt_ff1 + (size_t)l * D * F, ff_b1 + (size_t)l * F, ff1_bf, nullptr,
            BS, F, D, D, D, 1, nullptr, 0, 0, 0, 0);
        // FF2: split-K=2 (K=2048 -> 2x1024), f32 partials
        mfma_gemm<<<dim3(D / 128, BS / 128, 2), blk, 0, stream>>>(
            ff1_bf, wt_ff2 + (size_t)l * F * D, nullptr, nullptr, part0,
            BS, D, 1024, F, F, 4, nullptr, 1024, 1024, 0, (long)HSZ);
        // h = LN(h1 + p0 + p1 + b2)
        ln_res_kernel<<<dim3(BS), dim3(128), 0, stream>>>(
            h1_bf, part0, part1, ff_b2 + (size_t)l * D,
            ln_g + (size_t)l * 2 * D + D, ln_bb + (size_t)l * 2 * D + D, h_bf);
    }

    out_kernel<<<dim3(BS / 4), blk, 0, stream>>>(h_bf, out_W, out_b, out);
}

// Round 8
// 1205.927 us; speedup vs baseline: 1.0503x; 1.0503x over previous
//
#include <hip/hip_runtime.h>
#include <math.h>

#define B 16
#define S 512
#define IN 64
#define D 512
#define H 8
#define DK 64
#define L 6
#define F 2048
#define BS (B*S)          /* 8192 */
#define EPS 1e-5f

typedef short short8 __attribute__((ext_vector_type(8)));
typedef short short4v __attribute__((ext_vector_type(4)));
typedef float floatx4 __attribute__((ext_vector_type(4)));

static __device__ inline short f2bf(float x) {
    unsigned u = __float_as_uint(x);
    unsigned r = (u + 0x7fffu + ((u >> 16) & 1u)) >> 16;
    return (short)r;
}
static __device__ inline float bf2f(short s) {
    return __uint_as_float(((unsigned)(unsigned short)s) << 16);
}

// ---------------------------------------------------------------------------
// pe[k][d] = (1/S) * sum_q rel_emb[clip(q-k,-32,32)+32][d]   (closed form)
// ---------------------------------------------------------------------------
__global__ __launch_bounds__(256) void pe_kernel(const float* __restrict__ rel_emb,
                                                 float* __restrict__ pe) {
    int k = blockIdx.x;
    int d = threadIdx.x;
    float acc0 = 0.f, acc1 = 0.f;
    for (int r = 0; r < 65; ++r) {
        float w;
        if (r == 0)       w = (float)max(0, k - 31);
        else if (r == 64) w = (float)max(0, S - (k + 32));
        else {
            int qpos = k + r - 32;
            w = (qpos >= 0 && qpos < S) ? 1.f : 0.f;
        }
        acc0 += w * rel_emb[r * D + d];
        acc1 += w * rel_emb[r * D + d + 256];
    }
    pe[k * D + d]       = acc0 * (1.f / (float)S);
    pe[k * D + d + 256] = acc1 * (1.f / (float)S);
}

// ---------------------------------------------------------------------------
// Weight transpose + bf16 convert: src (z,K,N) f32 -> dst (z,N,K) bf16
// ---------------------------------------------------------------------------
__global__ __launch_bounds__(256) void wtrans_kernel(const float* __restrict__ src,
                                                     short* __restrict__ dst,
                                                     int K, int N) {
    __shared__ float Ls[32][33];
    const int z = blockIdx.z, kb = blockIdx.y, nb = blockIdx.x;
    const int tx = threadIdx.x & 31, ty = threadIdx.x >> 5;
    src += (size_t)z * K * N;
    dst += (size_t)z * K * N;
#pragma unroll
    for (int i = 0; i < 4; ++i)
        Ls[ty + i * 8][tx] = src[(size_t)(kb * 32 + ty + i * 8) * N + nb * 32 + tx];
    __syncthreads();
#pragma unroll
    for (int i = 0; i < 4; ++i) {
        int n = nb * 32 + ty + i * 8;
        dst[(size_t)n * K + kb * 32 + tx] = f2bf(Ls[tx][ty + i * 8]);
    }
}

// elementwise f32 -> bf16
__global__ __launch_bounds__(256) void cvt_kernel(const float* __restrict__ in,
                                                  short* __restrict__ out) {
    int i = (blockIdx.x * 256 + threadIdx.x) * 4;
    float4 v = *(const float4*)(in + i);
    short4v o;
    o.x = f2bf(v.x); o.y = f2bf(v.y); o.z = f2bf(v.z); o.w = f2bf(v.w);
    *(short4v*)(out + i) = o;
}

// ---------------------------------------------------------------------------
// Shared GEMM machinery: 3-stage vmcnt-gated K-loop (loads stay in flight
// across raw s_barriers; never vmcnt(0) mid-loop).
// ---------------------------------------------------------------------------
#define GLL(SRC, DST) __builtin_amdgcn_global_load_lds( \
    (const __attribute__((address_space(1))) void*)(SRC), \
    (__attribute__((address_space(3))) void*)(DST), 16, 0, 0)

// s_waitcnt imm: lgkmcnt=15 (no wait) | expcnt=7 (no wait) | vmcnt low bits
#define SWAIT4 __builtin_amdgcn_s_waitcnt(0x0F74)   /* wait until <=4 vmem */
#define SWAIT3 __builtin_amdgcn_s_waitcnt(0x0F73)   /* wait until <=3 vmem */
#define SWAIT0 __builtin_amdgcn_s_waitcnt(0x0F70)   /* wait until 0 vmem  */

// ---------------------------------------------------------------------------
// mfma_gemm: 128x128 tile, BK=32, 4 waves (2x2), 4x4 MFMA/wave.
// C = A(M,K) @ Bt(N,K)^T + bias
// mode 1: relu  2: +pe[row%S][col]
// mode 3: z-scatter: z<2 -> (B,H,S,DK) ; z==2 -> (B,H,DK,S)  [V^T direct]
// ---------------------------------------------------------------------------
#define KITER(CUR_A, CUR_B, NXT_A, NXT_B, I)                              \
  {                                                                       \
    if ((I) + 1 < niter) SWAIT4; else SWAIT0;                             \
    __builtin_amdgcn_s_barrier();                                         \
    const int kn_ = ((I) + 2) << 5;                                       \
    if (kn_ < K) {                                                        \
      GLL(Ag0 + kn_, NXT_A + so0); GLL(Ag1 + kn_, NXT_A + so1);           \
      GLL(Bg0 + kn_, NXT_B + so0); GLL(Bg1 + kn_, NXT_B + so1);           \
    }                                                                     \
    short8 af_[4], bf_[4];                                                \
    _Pragma("unroll")                                                     \
    for (int mt = 0; mt < 4; ++mt) {                                      \
      af_[mt] = *(const short8*)&CUR_A[((wm * 4 + mt) * 64 + slot) * 8];  \
      bf_[mt] = *(const short8*)&CUR_B[((wn * 4 + mt) * 64 + slot) * 8];  \
    }                                                                     \
    _Pragma("unroll")                                                     \
    for (int mt = 0; mt < 4; ++mt)                                        \
      _Pragma("unroll")                                                   \
      for (int nt = 0; nt < 4; ++nt)                                      \
        acc[mt][nt] = __builtin_amdgcn_mfma_f32_16x16x32_bf16(            \
            af_[mt], bf_[nt], acc[mt][nt], 0, 0, 0);                      \
  }

__global__ __launch_bounds__(256) void mfma_gemm(
    const short* __restrict__ A, const short* __restrict__ Bt,
    const float* __restrict__ bias, short* __restrict__ Cb,
    int M, int N, int K, int lda, int ldb, int mode,
    const float* __restrict__ pe, long wz, long bz, long cz)
{
    __shared__ short As0[4096], As1[4096], As2[4096];
    __shared__ short Bs0[4096], Bs1[4096], Bs2[4096];

    const int z = blockIdx.z;
    const short* Bz = Bt + (size_t)z * wz;

    const int t = threadIdx.x;
    const int w = t >> 6, lane = t & 63;
    const int wm = w >> 1, wn = w & 1;
    const int ln15 = lane & 15, lq = lane >> 4;
    const int bm = blockIdx.y, bn = blockIdx.x;

    // staging lane mapping (inverse of the XOR granule swizzle)
    const int ml = lane >> 2;
    const int kb = ((lane & 3) - (ml >> 1)) & 3;
    const short* Ag0 = A  + (size_t)(bm * 128 + w * 16 + ml)       * lda + kb * 8;
    const short* Ag1 = A  + (size_t)(bm * 128 + (w + 4) * 16 + ml) * lda + kb * 8;
    const short* Bg0 = Bz + (size_t)(bn * 128 + w * 16 + ml)       * ldb + kb * 8;
    const short* Bg1 = Bz + (size_t)(bn * 128 + (w + 4) * 16 + ml) * ldb + kb * 8;
    const int so0 = w * 512, so1 = (w + 4) * 512;

    floatx4 acc[4][4] = {};
    const int slot = ln15 * 4 + ((lq + (ln15 >> 1)) & 3);
    const int niter = K >> 5;

    GLL(Ag0, As0 + so0); GLL(Ag1, As0 + so1);
    GLL(Bg0, Bs0 + so0); GLL(Bg1, Bs0 + so1);
    if (niter > 1) {
        GLL(Ag0 + 32, As1 + so0); GLL(Ag1 + 32, As1 + so1);
        GLL(Bg0 + 32, Bs1 + so0); GLL(Bg1 + 32, Bs1 + so1);
    }

    int i = 0;
    for (; i + 3 <= niter; i += 3) {
        KITER(As0, Bs0, As2, Bs2, i);
        KITER(As1, Bs1, As0, Bs0, i + 1);
        KITER(As2, Bs2, As1, Bs1, i + 2);
    }
    if (i < niter)     KITER(As0, Bs0, As2, Bs2, i);
    if (i + 1 < niter) KITER(As1, Bs1, As0, Bs0, i + 1);

    short* Cbz = Cb + (size_t)z * cz;
    const float* bb = bias + (size_t)z * bz;
#pragma unroll
    for (int mt = 0; mt < 4; ++mt) {
#pragma unroll
        for (int nt = 0; nt < 4; ++nt) {
            const int col = bn * 128 + wn * 64 + nt * 16 + ln15;
            const int row0 = bm * 128 + wm * 64 + mt * 16 + lq * 4;
            const float bc = bb[col];
#pragma unroll
            for (int reg = 0; reg < 4; ++reg) {
                const int r = row0 + reg;
                float v = acc[mt][nt][reg] + bc;
                if (mode == 3) {
                    const int bi = r >> 9, si = r & (S - 1);
                    const int hh = col >> 6, dd = col & 63;
                    if (z == 2)   // V: store transposed (B,H,DK,S) directly
                        Cbz[(((size_t)(bi * H + hh) * DK + dd) * S + si)] = f2bf(v);
                    else
                        Cbz[(((size_t)(bi * H + hh) * S + si) * DK + dd)] = f2bf(v);
                } else {
                    if (mode == 1) v = fmaxf(v, 0.f);
                    else if (mode == 2) v += pe[(size_t)(r & (S - 1)) * D + col];
                    Cb[(size_t)r * N + col] = f2bf(v);
                }
            }
        }
    }
}

// ---------------------------------------------------------------------------
// mfma_gemm_n64: 128x64 tile, BK=32, 4 waves (4x1, 32 rows each), 2x4 MFMA.
// For small-N GEMMs (Wo, FF2): grid (N/64, M/128) = 512 blocks -> 2/CU
// without split-K partials. LDS 36 KB, acc 32 VGPR.
// ---------------------------------------------------------------------------
#define KITER64(CUR_A, CUR_B, NXT_A, NXT_B, I)                            \
  {                                                                       \
    if ((I) + 1 < niter) SWAIT3; else SWAIT0;                             \
    __builtin_amdgcn_s_barrier();                                         \
    const int kn_ = ((I) + 2) << 5;                                       \
    if (kn_ < K) {                                                        \
      GLL(Ag0 + kn_, NXT_A + so0); GLL(Ag1 + kn_, NXT_A + so1);           \
      GLL(Bg0 + kn_, NXT_B + sob);                                        \
    }                                                                     \
    short8 af_[2], bf_[4];                                                \
    _Pragma("unroll")                                                     \
    for (int mt = 0; mt < 2; ++mt)                                        \
      af_[mt] = *(const short8*)&CUR_A[((w * 2 + mt) * 64 + slot) * 8];   \
    _Pragma("unroll")                                                     \
    for (int nt = 0; nt < 4; ++nt)                                        \
      bf_[nt] = *(const short8*)&CUR_B[(nt * 64 + slot) * 8];             \
    _Pragma("unroll")                                                     \
    for (int mt = 0; mt < 2; ++mt)                                        \
      _Pragma("unroll")                                                   \
      for (int nt = 0; nt < 4; ++nt)                                      \
        acc[mt][nt] = __builtin_amdgcn_mfma_f32_16x16x32_bf16(            \
            af_[mt], bf_[nt], acc[mt][nt], 0, 0, 0);                      \
  }

__global__ __launch_bounds__(256) void mfma_gemm_n64(
    const short* __restrict__ A, const short* __restrict__ Bt,
    const float* __restrict__ bias, short* __restrict__ Cb,
    int M, int N, int K, int lda, int ldb, int mode)
{
    __shared__ short As0[4096], As1[4096], As2[4096];
    __shared__ short Bs0[2048], Bs1[2048], Bs2[2048];

    const int t = threadIdx.x;
    const int w = t >> 6, lane = t & 63;
    const int ln15 = lane & 15, lq = lane >> 4;
    const int bm = blockIdx.y, bn = blockIdx.x;

    const int ml = lane >> 2;
    const int kb = ((lane & 3) - (ml >> 1)) & 3;
    const short* Ag0 = A  + (size_t)(bm * 128 + w * 16 + ml)       * lda + kb * 8;
    const short* Ag1 = A  + (size_t)(bm * 128 + (w + 4) * 16 + ml) * lda + kb * 8;
    const short* Bg0 = Bt + (size_t)(bn * 64 + w * 16 + ml)        * ldb + kb * 8;
    const int so0 = w * 512, so1 = (w + 4) * 512, sob = w * 512;

    floatx4 acc[2][4] = {};
    const int slot = ln15 * 4 + ((lq + (ln15 >> 1)) & 3);
    const int niter = K >> 5;

    GLL(Ag0, As0 + so0); GLL(Ag1, As0 + so1); GLL(Bg0, Bs0 + sob);
    if (niter > 1) {
        GLL(Ag0 + 32, As1 + so0); GLL(Ag1 + 32, As1 + so1); GLL(Bg0 + 32, Bs1 + sob);
    }

    int i = 0;
    for (; i + 3 <= niter; i += 3) {
        KITER64(As0, Bs0, As2, Bs2, i);
        KITER64(As1, Bs1, As0, Bs0, i + 1);
        KITER64(As2, Bs2, As1, Bs1, i + 2);
    }
    if (i < niter)     KITER64(As0, Bs0, As2, Bs2, i);
    if (i + 1 < niter) KITER64(As1, Bs1, As0, Bs0, i + 1);

#pragma unroll
    for (int mt = 0; mt < 2; ++mt) {
#pragma unroll
        for (int nt = 0; nt < 4; ++nt) {
            const int col = bn * 64 + nt * 16 + ln15;
            const int row0 = bm * 128 + w * 32 + mt * 16 + lq * 4;
            const float bc = bias[col];
#pragma unroll
            for (int reg = 0; reg < 4; ++reg) {
                float v = acc[mt][nt][reg] + bc;
                if (mode == 1) v = fmaxf(v, 0.f);
                Cb[(size_t)(row0 + reg) * N + col] = f2bf(v);
            }
        }
    }
}

// ---------------------------------------------------------------------------
// bf16 MFMA flash attention. grid (S/64, B*H), 256 thr = 4 waves x 16 q-rows.
// q,k: (BH,S,DK) bf16 ; vt: (BH,DK,S) bf16 ; ctx out: (B,S,D) bf16
// ---------------------------------------------------------------------------
__global__ __launch_bounds__(256) void attn_mfma(
    const short* __restrict__ qg, const short* __restrict__ kg,
    const short* __restrict__ vtg, short* __restrict__ ctx)
{
    __shared__ short Ks[64 * 72];      // [kv][d]
    __shared__ short Vs[64 * 72];      // [dv][kv]
    __shared__ short Ps[4][16 * 72];   // per-wave P [m][kv] (wave-private)

    const int t = threadIdx.x;
    const int w = t >> 6, lane = t & 63;
    const int ln15 = lane & 15, lq = lane >> 4;
    const int bh = blockIdx.y, bi = bh >> 3, hh = bh & 7;
    const int qbase = blockIdx.x * 64 + w * 16;

    short8 qf0, qf1;
    {
        const short* qrow = qg + ((size_t)bh * S + qbase + ln15) * DK;
        qf0 = *(const short8*)(qrow + lq * 8);
        qf1 = *(const short8*)(qrow + 32 + lq * 8);
    }
    floatx4 o[4] = {};
    float mrow[4] = {-1e30f, -1e30f, -1e30f, -1e30f};
    float lrow[4] = {};

    const int sr = t >> 2, scg = t & 3;
    const short* kbase = kg  + (size_t)bh * S * DK;
    const short* vtb   = vtg + (size_t)bh * DK * S;

    for (int jt = 0; jt < S; jt += 64) {
        __syncthreads();
        *(short8*)&Ks[sr * 72 + scg * 8] =
            *(const short8*)(kbase + (size_t)(jt + sr) * DK + scg * 8);
        *(short8*)&Ks[sr * 72 + 32 + scg * 8] =
            *(const short8*)(kbase + (size_t)(jt + sr) * DK + 32 + scg * 8);
        *(short8*)&Vs[sr * 72 + scg * 8] =
            *(const short8*)(vtb + (size_t)sr * S + jt + scg * 8);
        *(short8*)&Vs[sr * 72 + 32 + scg * 8] =
            *(const short8*)(vtb + (size_t)sr * S + jt + 32 + scg * 8);
        __syncthreads();

        floatx4 sc[4];
#pragma unroll
        for (int nt = 0; nt < 4; ++nt) {
            floatx4 s4 = {};
            short8 kf0 = *(const short8*)&Ks[(nt * 16 + ln15) * 72 + lq * 8];
            short8 kf1 = *(const short8*)&Ks[(nt * 16 + ln15) * 72 + 32 + lq * 8];
            s4 = __builtin_amdgcn_mfma_f32_16x16x32_bf16(qf0, kf0, s4, 0, 0, 0);
            s4 = __builtin_amdgcn_mfma_f32_16x16x32_bf16(qf1, kf1, s4, 0, 0, 0);
#pragma unroll
            for (int r = 0; r < 4; ++r) s4[r] *= 0.125f;
            sc[nt] = s4;
        }

        float rmax[4];
#pragma unroll
        for (int r = 0; r < 4; ++r)
            rmax[r] = fmaxf(fmaxf(sc[0][r], sc[1][r]), fmaxf(sc[2][r], sc[3][r]));
#pragma unroll
        for (int off = 1; off < 16; off <<= 1)
#pragma unroll
            for (int r = 0; r < 4; ++r)
                rmax[r] = fmaxf(rmax[r], __shfl_xor(rmax[r], off));

        float mnew[4], alpha[4], psum[4];
#pragma unroll
        for (int r = 0; r < 4; ++r) {
            mnew[r]  = fmaxf(mrow[r], rmax[r]);
            alpha[r] = __expf(mrow[r] - mnew[r]);
            psum[r]  = 0.f;
        }
#pragma unroll
        for (int nt = 0; nt < 4; ++nt)
#pragma unroll
            for (int r = 0; r < 4; ++r) {
                float p = __expf(sc[nt][r] - mnew[r]);
                psum[r] += p;
                Ps[w][(lq * 4 + r) * 72 + nt * 16 + ln15] = f2bf(p);
            }
#pragma unroll
        for (int off = 1; off < 16; off <<= 1)
#pragma unroll
            for (int r = 0; r < 4; ++r)
                psum[r] += __shfl_xor(psum[r], off);
#pragma unroll
        for (int r = 0; r < 4; ++r) {
            lrow[r] = lrow[r] * alpha[r] + psum[r];
            mrow[r] = mnew[r];
        }
#pragma unroll
        for (int dv = 0; dv < 4; ++dv)
#pragma unroll
            for (int r = 0; r < 4; ++r)
                o[dv][r] *= alpha[r];

        // no barrier: Ps[w] is wave-private; within-wave LDS order via lgkmcnt
        short8 pf0 = *(const short8*)&Ps[w][ln15 * 72 + lq * 8];
        short8 pf1 = *(const short8*)&Ps[w][ln15 * 72 + 32 + lq * 8];
#pragma unroll
        for (int dv = 0; dv < 4; ++dv) {
            short8 vf0 = *(const short8*)&Vs[(dv * 16 + ln15) * 72 + lq * 8];
            short8 vf1 = *(const short8*)&Vs[(dv * 16 + ln15) * 72 + 32 + lq * 8];
            o[dv] = __builtin_amdgcn_mfma_f32_16x16x32_bf16(pf0, vf0, o[dv], 0, 0, 0);
            o[dv] = __builtin_amdgcn_mfma_f32_16x16x32_bf16(pf1, vf1, o[dv], 0, 0, 0);
        }
    }

    float inv[4];
#pragma unroll
    for (int r = 0; r < 4; ++r) inv[r] = 1.f / lrow[r];
#pragma unroll
    for (int dv = 0; dv < 4; ++dv)
#pragma unroll
        for (int r = 0; r < 4; ++r) {
            const int s = qbase + lq * 4 + r;
            const int col = hh * DK + dv * 16 + ln15;
            ctx[((size_t)bi * S + s) * D + col] = f2bf(o[dv][r] * inv[r]);
        }
}

// ---------------------------------------------------------------------------
// Fused residual + LayerNorm, bf16 in / bf16 out (f32 internal)
// ---------------------------------------------------------------------------
__global__ __launch_bounds__(128) void ln_kernel(
    const short* __restrict__ a, const short* __restrict__ bres,
    const float* __restrict__ g, const float* __restrict__ beta,
    short* __restrict__ outb)
{
    const int row = blockIdx.x;
    const int t = threadIdx.x;
    const size_t off = (size_t)row * D + t * 4;
    const short4v xa = *(const short4v*)(a + off);
    const short4v xb = *(const short4v*)(bres + off);
    float x0 = bf2f(xa.x) + bf2f(xb.x), x1 = bf2f(xa.y) + bf2f(xb.y);
    float x2 = bf2f(xa.z) + bf2f(xb.z), x3 = bf2f(xa.w) + bf2f(xb.w);
    float s  = x0 + x1 + x2 + x3;
    float s2 = x0 * x0 + x1 * x1 + x2 * x2 + x3 * x3;
#pragma unroll
    for (int o = 32; o > 0; o >>= 1) {
        s  += __shfl_down(s, o);
        s2 += __shfl_down(s2, o);
    }
    __shared__ float red[2][2];
    const int wave = t >> 6;
    if ((t & 63) == 0) { red[wave][0] = s; red[wave][1] = s2; }
    __syncthreads();
    s  = red[0][0] + red[1][0];
    s2 = red[0][1] + red[1][1];
    const float mu  = s * (1.f / (float)D);
    const float var = s2 * (1.f / (float)D) - mu * mu;
    const float r   = rsqrtf(var + EPS);
    const float4 gg = *(const float4*)(g    + t * 4);
    const float4 bb = *(const float4*)(beta + t * 4);
    short4v ob;
    ob.x = f2bf((x0 - mu) * r * gg.x + bb.x);
    ob.y = f2bf((x1 - mu) * r * gg.y + bb.y);
    ob.z = f2bf((x2 - mu) * r * gg.z + bb.z);
    ob.w = f2bf((x3 - mu) * r * gg.w + bb.w);
    *(short4v*)(outb + off) = ob;
}

// ---------------------------------------------------------------------------
// out[row] = h[row,:] . out_W + out_b ; one wave per row (h is bf16)
// ---------------------------------------------------------------------------
__global__ __launch_bounds__(256) void out_kernel(
    const short* __restrict__ h, const float* __restrict__ ow,
    const float* __restrict__ ob, float* __restrict__ out)
{
    const int wave = threadIdx.x >> 6;
    const int lane = threadIdx.x & 63;
    const int row  = blockIdx.x * 4 + wave;
    const short* hp = h + (size_t)row * D;
    float s = 0.f;
#pragma unroll
    for (int u = 0; u < 8; ++u) {
        int d = lane + u * 64;
        s += bf2f(hp[d]) * ow[d];
    }
#pragma unroll
    for (int o = 32; o > 0; o >>= 1) s += __shfl_down(s, o);
    if (lane == 0) out[row] = s + ob[0];
}

// ---------------------------------------------------------------------------
extern "C" void kernel_launch(void* const* d_in, const int* in_sizes, int n_in,
                              void* d_out, int out_size, void* d_ws, size_t ws_size,
                              hipStream_t stream) {
    const float* x       = (const float*)d_in[0];
    const float* in_W    = (const float*)d_in[1];
    const float* in_b    = (const float*)d_in[2];
    const float* rel_emb = (const float*)d_in[3];
    const float* qkvo_W  = (const float*)d_in[4];
    const float* qkvo_b  = (const float*)d_in[5];
    const float* ln_g    = (const float*)d_in[6];
    const float* ln_bb   = (const float*)d_in[7];
    const float* ff_W1   = (const float*)d_in[8];
    const float* ff_b1   = (const float*)d_in[9];
    const float* ff_W2   = (const float*)d_in[10];
    const float* ff_b2   = (const float*)d_in[11];
    const float* out_W   = (const float*)d_in[12];
    const float* out_b   = (const float*)d_in[13];
    float* out = (float*)d_out;

    const size_t HSZ = (size_t)BS * D;              // 4.19M elems
    float* pe     = (float*)d_ws;                   // S*D f32
    short* h_bf   = (short*)(pe + (size_t)S * D);
    short* h1_bf  = h_bf  + HSZ;
    short* tmp_bf = h1_bf + HSZ;
    short* qkv_bf = tmp_bf + HSZ;                   // 4*HSZ: q,k,vt,ctx (ff1 alias)
    short* xb     = qkv_bf + 4 * HSZ;               // BS*IN
    short* wt_qkvo = xb + (size_t)BS * IN;          // L*4*D*D
    short* wt_ff1  = wt_qkvo + (size_t)L * 4 * D * D;  // L*D*F
    short* wt_ff2  = wt_ff1  + (size_t)L * D * F;      // L*F*D
    short* wt_in   = wt_ff2  + (size_t)L * F * D;      // D*IN

    const size_t CZ = (size_t)B * H * S * DK;       // == HSZ
    short* qb = qkv_bf;
    short* kb = qkv_bf + CZ;
    short* vt = qkv_bf + 2 * CZ;                    // V^T written directly by qkv GEMM
    short* ctx_bf = qkv_bf + 3 * CZ;
    short* ff1_bf = qkv_bf;                         // alias (qkv dead after Wo)

    dim3 blk(256);

    // --- prologue: pe, input cvt, ALL weight transposes (hoisted) ---
    pe_kernel<<<dim3(S), blk, 0, stream>>>(rel_emb, pe);
    cvt_kernel<<<dim3(BS * IN / 1024), blk, 0, stream>>>(x, xb);
    wtrans_kernel<<<dim3(D / 32, IN / 32, 1), blk, 0, stream>>>(in_W, wt_in, IN, D);
    wtrans_kernel<<<dim3(D / 32, D / 32, 4 * L), blk, 0, stream>>>(qkvo_W, wt_qkvo, D, D);
    wtrans_kernel<<<dim3(F / 32, D / 32, L), blk, 0, stream>>>(ff_W1, wt_ff1, D, F);
    wtrans_kernel<<<dim3(D / 32, F / 32, L), blk, 0, stream>>>(ff_W2, wt_ff2, F, D);

    // h = x @ in_W + in_b + pe   (bf16)
    mfma_gemm<<<dim3(D / 128, BS / 128, 1), blk, 0, stream>>>(
        xb, wt_in, in_b, h_bf, BS, D, IN, IN, IN, 2, pe, 0, 0, 0);

    for (int l = 0; l < L; ++l) {
        const float* bl = qkvo_b + (size_t)l * 4 * D;
        // q,k,v projections; V scattered directly as V^T (no vtrans kernel)
        mfma_gemm<<<dim3(D / 128, BS / 128, 3), blk, 0, stream>>>(
            h_bf, wt_qkvo + (size_t)l * 4 * D * D, bl, qkv_bf,
            BS, D, D, D, D, 3, nullptr, (long)D * D, (long)D, (long)CZ);
        attn_mfma<<<dim3(S / 64, B * H), blk, 0, stream>>>(qb, kb, vt, ctx_bf);
        // tmp = ctx @ W_o + b_o   (128x64 tiles, 512 blocks, no split-K)
        mfma_gemm_n64<<<dim3(D / 64, BS / 128), blk, 0, stream>>>(
            ctx_bf, wt_qkvo + (size_t)(l * 4 + 3) * D * D, bl + 3 * D, tmp_bf,
            BS, D, D, D, D, 0);
        // h1 = LN(h + tmp)
        ln_kernel<<<dim3(BS), dim3(128), 0, stream>>>(
            h_bf, tmp_bf, ln_g + (size_t)l * 2 * D, ln_bb + (size_t)l * 2 * D, h1_bf);
        // ff1 = relu(h1 @ W1 + b1)
        mfma_gemm<<<dim3(F / 128, BS / 128, 1), blk, 0, stream>>>(
            h1_bf, wt_ff1 + (size_t)l * D * F, ff_b1 + (size_t)l * F, ff1_bf,
            BS, F, D, D, D, 1, nullptr, 0, 0, 0);
        // tmp = ff1 @ W2 + b2   (128x64 tiles, K=2048 full, 512 blocks)
        mfma_gemm_n64<<<dim3(D / 64, BS / 128), blk, 0, stream>>>(
            ff1_bf, wt_ff2 + (size_t)l * F * D, ff_b2 + (size_t)l * D, tmp_bf,
            BS, D, F, F, F, 0);
        // h = LN(h1 + tmp)
        ln_kernel<<<dim3(BS), dim3(128), 0, stream>>>(
            h1_bf, tmp_bf, ln_g + (size_t)l * 2 * D + D, ln_bb + (size_t)l * 2 * D + D,
            h_bf);
    }

    out_kernel<<<dim3(BS / 4), blk, 0, stream>>>(h_bf, out_W, out_b, out);
}

// Round 9
// 1102.257 us; speedup vs baseline: 1.1491x; 1.0941x over previous
//
#include <hip/hip_runtime.h>
#include <math.h>

#define B 16
#define S 512
#define IN 64
#define D 512
#define H 8
#define DK 64
#define L 6
#define F 2048
#define BS (B*S)          /* 8192 */
#define EPS 1e-5f

typedef short short8 __attribute__((ext_vector_type(8)));
typedef short short4v __attribute__((ext_vector_type(4)));
typedef float floatx4 __attribute__((ext_vector_type(4)));

static __device__ inline short f2bf(float x) {
    unsigned u = __float_as_uint(x);
    unsigned r = (u + 0x7fffu + ((u >> 16) & 1u)) >> 16;
    return (short)r;
}
static __device__ inline float bf2f(short s) {
    return __uint_as_float(((unsigned)(unsigned short)s) << 16);
}

// ---------------------------------------------------------------------------
// pe[k][d] = (1/S) * sum_q rel_emb[clip(q-k,-32,32)+32][d]   (closed form)
// ---------------------------------------------------------------------------
__global__ __launch_bounds__(256) void pe_kernel(const float* __restrict__ rel_emb,
                                                 float* __restrict__ pe) {
    int k = blockIdx.x;
    int d = threadIdx.x;
    float acc0 = 0.f, acc1 = 0.f;
    for (int r = 0; r < 65; ++r) {
        float w;
        if (r == 0)       w = (float)max(0, k - 31);
        else if (r == 64) w = (float)max(0, S - (k + 32));
        else {
            int qpos = k + r - 32;
            w = (qpos >= 0 && qpos < S) ? 1.f : 0.f;
        }
        acc0 += w * rel_emb[r * D + d];
        acc1 += w * rel_emb[r * D + d + 256];
    }
    pe[k * D + d]       = acc0 * (1.f / (float)S);
    pe[k * D + d + 256] = acc1 * (1.f / (float)S);
}

// ---------------------------------------------------------------------------
// Weight transpose + bf16 convert: src (z,K,N) f32 -> dst (z,N,K) bf16
// ---------------------------------------------------------------------------
__global__ __launch_bounds__(256) void wtrans_kernel(const float* __restrict__ src,
                                                     short* __restrict__ dst,
                                                     int K, int N) {
    __shared__ float Ls[32][33];
    const int z = blockIdx.z, kb = blockIdx.y, nb = blockIdx.x;
    const int tx = threadIdx.x & 31, ty = threadIdx.x >> 5;
    src += (size_t)z * K * N;
    dst += (size_t)z * K * N;
#pragma unroll
    for (int i = 0; i < 4; ++i)
        Ls[ty + i * 8][tx] = src[(size_t)(kb * 32 + ty + i * 8) * N + nb * 32 + tx];
    __syncthreads();
#pragma unroll
    for (int i = 0; i < 4; ++i) {
        int n = nb * 32 + ty + i * 8;
        dst[(size_t)n * K + kb * 32 + tx] = f2bf(Ls[tx][ty + i * 8]);
    }
}

// elementwise f32 -> bf16
__global__ __launch_bounds__(256) void cvt_kernel(const float* __restrict__ in,
                                                  short* __restrict__ out) {
    int i = (blockIdx.x * 256 + threadIdx.x) * 4;
    float4 v = *(const float4*)(in + i);
    short4v o;
    o.x = f2bf(v.x); o.y = f2bf(v.y); o.z = f2bf(v.z); o.w = f2bf(v.w);
    *(short4v*)(out + i) = o;
}

// ---------------------------------------------------------------------------
// Shared GEMM machinery: 3-stage vmcnt-gated K-loop (loads stay in flight
// across raw s_barriers; never vmcnt(0) mid-loop).
// ---------------------------------------------------------------------------
#define GLL(SRC, DST) __builtin_amdgcn_global_load_lds( \
    (const __attribute__((address_space(1))) void*)(SRC), \
    (__attribute__((address_space(3))) void*)(DST), 16, 0, 0)

// s_waitcnt imm: lgkmcnt=15 (no wait) | expcnt=7 (no wait) | vmcnt low bits
#define SWAIT4 __builtin_amdgcn_s_waitcnt(0x0F74)   /* wait until <=4 vmem */
#define SWAIT3 __builtin_amdgcn_s_waitcnt(0x0F73)   /* wait until <=3 vmem */
#define SWAIT0 __builtin_amdgcn_s_waitcnt(0x0F70)   /* wait until 0 vmem  */

// ---------------------------------------------------------------------------
// mfma_gemm: 128x128 tile, BK=32, 4 waves (2x2), 4x4 MFMA/wave.
// XCD swizzle: blocks sharing an A-tile (same bm) colocate on one XCD so
// GLL staging hits the local L2 (per-XCD A-slice 1MB + B <=2MB < 4MB L2).
// Requires gridDim.y == 64 and gridDim.x*gridDim.y % 8 == 0 (true here).
// mode 1: relu  2: +pe[row%S][col]
// mode 3: z-scatter: z<2 -> (B,H,S,DK) ; z==2 -> (B,H,DK,S)  [V^T direct]
// ---------------------------------------------------------------------------
#define KITER(CUR_A, CUR_B, NXT_A, NXT_B, I)                              \
  {                                                                       \
    if ((I) + 1 < niter) SWAIT4; else SWAIT0;                             \
    __builtin_amdgcn_s_barrier();                                         \
    const int kn_ = ((I) + 2) << 5;                                       \
    if (kn_ < K) {                                                        \
      GLL(Ag0 + kn_, NXT_A + so0); GLL(Ag1 + kn_, NXT_A + so1);           \
      GLL(Bg0 + kn_, NXT_B + so0); GLL(Bg1 + kn_, NXT_B + so1);           \
    }                                                                     \
    short8 af_[4], bf_[4];                                                \
    _Pragma("unroll")                                                     \
    for (int mt = 0; mt < 4; ++mt) {                                      \
      af_[mt] = *(const short8*)&CUR_A[((wm * 4 + mt) * 64 + slot) * 8];  \
      bf_[mt] = *(const short8*)&CUR_B[((wn * 4 + mt) * 64 + slot) * 8];  \
    }                                                                     \
    _Pragma("unroll")                                                     \
    for (int mt = 0; mt < 4; ++mt)                                        \
      _Pragma("unroll")                                                   \
      for (int nt = 0; nt < 4; ++nt)                                      \
        acc[mt][nt] = __builtin_amdgcn_mfma_f32_16x16x32_bf16(            \
            af_[mt], bf_[nt], acc[mt][nt], 0, 0, 0);                      \
  }

__global__ __launch_bounds__(256) void mfma_gemm(
    const short* __restrict__ A, const short* __restrict__ Bt,
    const float* __restrict__ bias, short* __restrict__ Cb,
    int M, int N, int K, int lda, int ldb, int mode,
    const float* __restrict__ pe, long wz, long bz, long cz)
{
    __shared__ short As0[4096], As1[4096], As2[4096];
    __shared__ short Bs0[4096], Bs1[4096], Bs2[4096];

    const int z = blockIdx.z;
    const short* Bz = Bt + (size_t)z * wz;

    const int t = threadIdx.x;
    const int w = t >> 6, lane = t & 63;
    const int wm = w >> 1, wn = w & 1;
    const int ln15 = lane & 15, lq = lane >> 4;

    // XCD-aware swizzle: xcd = linear%8 owns bm in [xcd*8, xcd*8+8)
    const int gx = gridDim.x;
    const int rlin = blockIdx.x + gx * blockIdx.y;
    const int xcd = rlin & 7;
    const int j = rlin >> 3;
    const int bm = xcd * 8 + j / gx;
    const int bn = j % gx;

    // staging lane mapping (inverse of the XOR granule swizzle)
    const int ml = lane >> 2;
    const int kb = ((lane & 3) - (ml >> 1)) & 3;
    const short* Ag0 = A  + (size_t)(bm * 128 + w * 16 + ml)       * lda + kb * 8;
    const short* Ag1 = A  + (size_t)(bm * 128 + (w + 4) * 16 + ml) * lda + kb * 8;
    const short* Bg0 = Bz + (size_t)(bn * 128 + w * 16 + ml)       * ldb + kb * 8;
    const short* Bg1 = Bz + (size_t)(bn * 128 + (w + 4) * 16 + ml) * ldb + kb * 8;
    const int so0 = w * 512, so1 = (w + 4) * 512;

    floatx4 acc[4][4] = {};
    const int slot = ln15 * 4 + ((lq + (ln15 >> 1)) & 3);
    const int niter = K >> 5;

    GLL(Ag0, As0 + so0); GLL(Ag1, As0 + so1);
    GLL(Bg0, Bs0 + so0); GLL(Bg1, Bs0 + so1);
    if (niter > 1) {
        GLL(Ag0 + 32, As1 + so0); GLL(Ag1 + 32, As1 + so1);
        GLL(Bg0 + 32, Bs1 + so0); GLL(Bg1 + 32, Bs1 + so1);
    }

    int i = 0;
    for (; i + 3 <= niter; i += 3) {
        KITER(As0, Bs0, As2, Bs2, i);
        KITER(As1, Bs1, As0, Bs0, i + 1);
        KITER(As2, Bs2, As1, Bs1, i + 2);
    }
    if (i < niter)     KITER(As0, Bs0, As2, Bs2, i);
    if (i + 1 < niter) KITER(As1, Bs1, As0, Bs0, i + 1);

    short* Cbz = Cb + (size_t)z * cz;
    const float* bb = bias + (size_t)z * bz;
#pragma unroll
    for (int mt = 0; mt < 4; ++mt) {
#pragma unroll
        for (int nt = 0; nt < 4; ++nt) {
            const int col = bn * 128 + wn * 64 + nt * 16 + ln15;
            const int row0 = bm * 128 + wm * 64 + mt * 16 + lq * 4;
            const float bc = bb[col];
#pragma unroll
            for (int reg = 0; reg < 4; ++reg) {
                const int r = row0 + reg;
                float v = acc[mt][nt][reg] + bc;
                if (mode == 3) {
                    const int bi = r >> 9, si = r & (S - 1);
                    const int hh = col >> 6, dd = col & 63;
                    if (z == 2)   // V: store transposed (B,H,DK,S) directly
                        Cbz[(((size_t)(bi * H + hh) * DK + dd) * S + si)] = f2bf(v);
                    else
                        Cbz[(((size_t)(bi * H + hh) * S + si) * DK + dd)] = f2bf(v);
                } else {
                    if (mode == 1) v = fmaxf(v, 0.f);
                    else if (mode == 2) v += pe[(size_t)(r & (S - 1)) * D + col];
                    Cb[(size_t)r * N + col] = f2bf(v);
                }
            }
        }
    }
}

// ---------------------------------------------------------------------------
// mfma_gemm_n64: 128x64 tile, BK=32, 4 waves (4x1, 32 rows each), 2x4 MFMA.
// XCD swizzle: gridDim.x == 8 assumed (N=512); xcd owns 8 bm-rows.
// ---------------------------------------------------------------------------
#define KITER64(CUR_A, CUR_B, NXT_A, NXT_B, I)                            \
  {                                                                       \
    if ((I) + 1 < niter) SWAIT3; else SWAIT0;                             \
    __builtin_amdgcn_s_barrier();                                         \
    const int kn_ = ((I) + 2) << 5;                                       \
    if (kn_ < K) {                                                        \
      GLL(Ag0 + kn_, NXT_A + so0); GLL(Ag1 + kn_, NXT_A + so1);           \
      GLL(Bg0 + kn_, NXT_B + sob);                                        \
    }                                                                     \
    short8 af_[2], bf_[4];                                                \
    _Pragma("unroll")                                                     \
    for (int mt = 0; mt < 2; ++mt)                                        \
      af_[mt] = *(const short8*)&CUR_A[((w * 2 + mt) * 64 + slot) * 8];   \
    _Pragma("unroll")                                                     \
    for (int nt = 0; nt < 4; ++nt)                                        \
      bf_[nt] = *(const short8*)&CUR_B[(nt * 64 + slot) * 8];             \
    _Pragma("unroll")                                                     \
    for (int mt = 0; mt < 2; ++mt)                                        \
      _Pragma("unroll")                                                   \
      for (int nt = 0; nt < 4; ++nt)                                      \
        acc[mt][nt] = __builtin_amdgcn_mfma_f32_16x16x32_bf16(            \
            af_[mt], bf_[nt], acc[mt][nt], 0, 0, 0);                      \
  }

__global__ __launch_bounds__(256) void mfma_gemm_n64(
    const short* __restrict__ A, const short* __restrict__ Bt,
    const float* __restrict__ bias, short* __restrict__ Cb,
    int M, int N, int K, int lda, int ldb, int mode)
{
    __shared__ short As0[4096], As1[4096], As2[4096];
    __shared__ short Bs0[2048], Bs1[2048], Bs2[2048];

    const int t = threadIdx.x;
    const int w = t >> 6, lane = t & 63;
    const int ln15 = lane & 15, lq = lane >> 4;

    // XCD swizzle (gridDim.x == 8): xcd owns bm in [xcd*8, xcd*8+8)
    const int rlin = blockIdx.x + 8 * blockIdx.y;
    const int xcd = rlin & 7;
    const int j = rlin >> 3;
    const int bm = xcd * 8 + (j >> 3);
    const int bn = j & 7;

    const int ml = lane >> 2;
    const int kb = ((lane & 3) - (ml >> 1)) & 3;
    const short* Ag0 = A  + (size_t)(bm * 128 + w * 16 + ml)       * lda + kb * 8;
    const short* Ag1 = A  + (size_t)(bm * 128 + (w + 4) * 16 + ml) * lda + kb * 8;
    const short* Bg0 = Bt + (size_t)(bn * 64 + w * 16 + ml)        * ldb + kb * 8;
    const int so0 = w * 512, so1 = (w + 4) * 512, sob = w * 512;

    floatx4 acc[2][4] = {};
    const int slot = ln15 * 4 + ((lq + (ln15 >> 1)) & 3);
    const int niter = K >> 5;

    GLL(Ag0, As0 + so0); GLL(Ag1, As0 + so1); GLL(Bg0, Bs0 + sob);
    if (niter > 1) {
        GLL(Ag0 + 32, As1 + so0); GLL(Ag1 + 32, As1 + so1); GLL(Bg0 + 32, Bs1 + sob);
    }

    int i = 0;
    for (; i + 3 <= niter; i += 3) {
        KITER64(As0, Bs0, As2, Bs2, i);
        KITER64(As1, Bs1, As0, Bs0, i + 1);
        KITER64(As2, Bs2, As1, Bs1, i + 2);
    }
    if (i < niter)     KITER64(As0, Bs0, As2, Bs2, i);
    if (i + 1 < niter) KITER64(As1, Bs1, As0, Bs0, i + 1);

#pragma unroll
    for (int mt = 0; mt < 2; ++mt) {
#pragma unroll
        for (int nt = 0; nt < 4; ++nt) {
            const int col = bn * 64 + nt * 16 + ln15;
            const int row0 = bm * 128 + w * 32 + mt * 16 + lq * 4;
            const float bc = bias[col];
#pragma unroll
            for (int reg = 0; reg < 4; ++reg) {
                float v = acc[mt][nt][reg] + bc;
                if (mode == 1) v = fmaxf(v, 0.f);
                Cb[(size_t)(row0 + reg) * N + col] = f2bf(v);
            }
        }
    }
}

// ---------------------------------------------------------------------------
// bf16 MFMA flash attention. grid (S/64=8, B*H=128), 4 waves x 16 q-rows.
// XCD swizzle: xcd owns bh in [xcd*16, xcd*16+16) so the 8 blocks sharing
// one (b,h)'s K/V colocate on one XCD L2.
// q,k: (BH,S,DK) bf16 ; vt: (BH,DK,S) bf16 ; ctx out: (B,S,D) bf16
// ---------------------------------------------------------------------------
__global__ __launch_bounds__(256) void attn_mfma(
    const short* __restrict__ qg, const short* __restrict__ kg,
    const short* __restrict__ vtg, short* __restrict__ ctx)
{
    __shared__ short Ks[64 * 72];      // [kv][d]
    __shared__ short Vs[64 * 72];      // [dv][kv]
    __shared__ short Ps[4][16 * 72];   // per-wave P [m][kv] (wave-private)

    const int t = threadIdx.x;
    const int w = t >> 6, lane = t & 63;
    const int ln15 = lane & 15, lq = lane >> 4;

    const int rlin = blockIdx.x + 8 * blockIdx.y;
    const int xcd = rlin & 7;
    const int j = rlin >> 3;
    const int bh = xcd * 16 + (j >> 3);
    const int qc = j & 7;

    const int bi = bh >> 3, hh = bh & 7;
    const int qbase = qc * 64 + w * 16;

    short8 qf0, qf1;
    {
        const short* qrow = qg + ((size_t)bh * S + qbase + ln15) * DK;
        qf0 = *(const short8*)(qrow + lq * 8);
        qf1 = *(const short8*)(qrow + 32 + lq * 8);
    }
    floatx4 o[4] = {};
    float mrow[4] = {-1e30f, -1e30f, -1e30f, -1e30f};
    float lrow[4] = {};

    const int sr = t >> 2, scg = t & 3;
    const short* kbase = kg  + (size_t)bh * S * DK;
    const short* vtb   = vtg + (size_t)bh * DK * S;

    for (int jt = 0; jt < S; jt += 64) {
        __syncthreads();
        *(short8*)&Ks[sr * 72 + scg * 8] =
            *(const short8*)(kbase + (size_t)(jt + sr) * DK + scg * 8);
        *(short8*)&Ks[sr * 72 + 32 + scg * 8] =
            *(const short8*)(kbase + (size_t)(jt + sr) * DK + 32 + scg * 8);
        *(short8*)&Vs[sr * 72 + scg * 8] =
            *(const short8*)(vtb + (size_t)sr * S + jt + scg * 8);
        *(short8*)&Vs[sr * 72 + 32 + scg * 8] =
            *(const short8*)(vtb + (size_t)sr * S + jt + 32 + scg * 8);
        __syncthreads();

        floatx4 sc[4];
#pragma unroll
        for (int nt = 0; nt < 4; ++nt) {
            floatx4 s4 = {};
            short8 kf0 = *(const short8*)&Ks[(nt * 16 + ln15) * 72 + lq * 8];
            short8 kf1 = *(const short8*)&Ks[(nt * 16 + ln15) * 72 + 32 + lq * 8];
            s4 = __builtin_amdgcn_mfma_f32_16x16x32_bf16(qf0, kf0, s4, 0, 0, 0);
            s4 = __builtin_amdgcn_mfma_f32_16x16x32_bf16(qf1, kf1, s4, 0, 0, 0);
#pragma unroll
            for (int r = 0; r < 4; ++r) s4[r] *= 0.125f;
            sc[nt] = s4;
        }

        float rmax[4];
#pragma unroll
        for (int r = 0; r < 4; ++r)
            rmax[r] = fmaxf(fmaxf(sc[0][r], sc[1][r]), fmaxf(sc[2][r], sc[3][r]));
#pragma unroll
        for (int off = 1; off < 16; off <<= 1)
#pragma unroll
            for (int r = 0; r < 4; ++r)
                rmax[r] = fmaxf(rmax[r], __shfl_xor(rmax[r], off));

        float mnew[4], alpha[4], psum[4];
#pragma unroll
        for (int r = 0; r < 4; ++r) {
            mnew[r]  = fmaxf(mrow[r], rmax[r]);
            alpha[r] = __expf(mrow[r] - mnew[r]);
            psum[r]  = 0.f;
        }
#pragma unroll
        for (int nt = 0; nt < 4; ++nt)
#pragma unroll
            for (int r = 0; r < 4; ++r) {
                float p = __expf(sc[nt][r] - mnew[r]);
                psum[r] += p;
                Ps[w][(lq * 4 + r) * 72 + nt * 16 + ln15] = f2bf(p);
            }
#pragma unroll
        for (int off = 1; off < 16; off <<= 1)
#pragma unroll
            for (int r = 0; r < 4; ++r)
                psum[r] += __shfl_xor(psum[r], off);
#pragma unroll
        for (int r = 0; r < 4; ++r) {
            lrow[r] = lrow[r] * alpha[r] + psum[r];
            mrow[r] = mnew[r];
        }
#pragma unroll
        for (int dv = 0; dv < 4; ++dv)
#pragma unroll
            for (int r = 0; r < 4; ++r)
                o[dv][r] *= alpha[r];

        // no barrier: Ps[w] is wave-private; within-wave LDS order via lgkmcnt
        short8 pf0 = *(const short8*)&Ps[w][ln15 * 72 + lq * 8];
        short8 pf1 = *(const short8*)&Ps[w][ln15 * 72 + 32 + lq * 8];
#pragma unroll
        for (int dv = 0; dv < 4; ++dv) {
            short8 vf0 = *(const short8*)&Vs[(dv * 16 + ln15) * 72 + lq * 8];
            short8 vf1 = *(const short8*)&Vs[(dv * 16 + ln15) * 72 + 32 + lq * 8];
            o[dv] = __builtin_amdgcn_mfma_f32_16x16x32_bf16(pf0, vf0, o[dv], 0, 0, 0);
            o[dv] = __builtin_amdgcn_mfma_f32_16x16x32_bf16(pf1, vf1, o[dv], 0, 0, 0);
        }
    }

    float inv[4];
#pragma unroll
    for (int r = 0; r < 4; ++r) inv[r] = 1.f / lrow[r];
#pragma unroll
    for (int dv = 0; dv < 4; ++dv)
#pragma unroll
        for (int r = 0; r < 4; ++r) {
            const int s = qbase + lq * 4 + r;
            const int col = hh * DK + dv * 16 + ln15;
            ctx[((size_t)bi * S + s) * D + col] = f2bf(o[dv][r] * inv[r]);
        }
}

// ---------------------------------------------------------------------------
// Fused residual + LayerNorm, bf16 in / bf16 out (f32 internal)
// ---------------------------------------------------------------------------
__global__ __launch_bounds__(128) void ln_kernel(
    const short* __restrict__ a, const short* __restrict__ bres,
    const float* __restrict__ g, const float* __restrict__ beta,
    short* __restrict__ outb)
{
    const int row = blockIdx.x;
    const int t = threadIdx.x;
    const size_t off = (size_t)row * D + t * 4;
    const short4v xa = *(const short4v*)(a + off);
    const short4v xb = *(const short4v*)(bres + off);
    float x0 = bf2f(xa.x) + bf2f(xb.x), x1 = bf2f(xa.y) + bf2f(xb.y);
    float x2 = bf2f(xa.z) + bf2f(xb.z), x3 = bf2f(xa.w) + bf2f(xb.w);
    float s  = x0 + x1 + x2 + x3;
    float s2 = x0 * x0 + x1 * x1 + x2 * x2 + x3 * x3;
#pragma unroll
    for (int o = 32; o > 0; o >>= 1) {
        s  += __shfl_down(s, o);
        s2 += __shfl_down(s2, o);
    }
    __shared__ float red[2][2];
    const int wave = t >> 6;
    if ((t & 63) == 0) { red[wave][0] = s; red[wave][1] = s2; }
    __syncthreads();
    s  = red[0][0] + red[1][0];
    s2 = red[0][1] + red[1][1];
    const float mu  = s * (1.f / (float)D);
    const float var = s2 * (1.f / (float)D) - mu * mu;
    const float r   = rsqrtf(var + EPS);
    const float4 gg = *(const float4*)(g    + t * 4);
    const float4 bb = *(const float4*)(beta + t * 4);
    short4v ob;
    ob.x = f2bf((x0 - mu) * r * gg.x + bb.x);
    ob.y = f2bf((x1 - mu) * r * gg.y + bb.y);
    ob.z = f2bf((x2 - mu) * r * gg.z + bb.z);
    ob.w = f2bf((x3 - mu) * r * gg.w + bb.w);
    *(short4v*)(outb + off) = ob;
}

// ---------------------------------------------------------------------------
// out[row] = h[row,:] . out_W + out_b ; one wave per row (h is bf16)
// ---------------------------------------------------------------------------
__global__ __launch_bounds__(256) void out_kernel(
    const short* __restrict__ h, const float* __restrict__ ow,
    const float* __restrict__ ob, float* __restrict__ out)
{
    const int wave = threadIdx.x >> 6;
    const int lane = threadIdx.x & 63;
    const int row  = blockIdx.x * 4 + wave;
    const short* hp = h + (size_t)row * D;
    float s = 0.f;
#pragma unroll
    for (int u = 0; u < 8; ++u) {
        int d = lane + u * 64;
        s += bf2f(hp[d]) * ow[d];
    }
#pragma unroll
    for (int o = 32; o > 0; o >>= 1) s += __shfl_down(s, o);
    if (lane == 0) out[row] = s + ob[0];
}

// ---------------------------------------------------------------------------
extern "C" void kernel_launch(void* const* d_in, const int* in_sizes, int n_in,
                              void* d_out, int out_size, void* d_ws, size_t ws_size,
                              hipStream_t stream) {
    const float* x       = (const float*)d_in[0];
    const float* in_W    = (const float*)d_in[1];
    const float* in_b    = (const float*)d_in[2];
    const float* rel_emb = (const float*)d_in[3];
    const float* qkvo_W  = (const float*)d_in[4];
    const float* qkvo_b  = (const float*)d_in[5];
    const float* ln_g    = (const float*)d_in[6];
    const float* ln_bb   = (const float*)d_in[7];
    const float* ff_W1   = (const float*)d_in[8];
    const float* ff_b1   = (const float*)d_in[9];
    const float* ff_W2   = (const float*)d_in[10];
    const float* ff_b2   = (const float*)d_in[11];
    const float* out_W   = (const float*)d_in[12];
    const float* out_b   = (const float*)d_in[13];
    float* out = (float*)d_out;

    const size_t HSZ = (size_t)BS * D;              // 4.19M elems
    float* pe     = (float*)d_ws;                   // S*D f32
    short* h_bf   = (short*)(pe + (size_t)S * D);
    short* h1_bf  = h_bf  + HSZ;
    short* tmp_bf = h1_bf + HSZ;
    short* qkv_bf = tmp_bf + HSZ;                   // 4*HSZ: q,k,vt,ctx (ff1 alias)
    short* xb     = qkv_bf + 4 * HSZ;               // BS*IN
    short* wt_qkvo = xb + (size_t)BS * IN;          // L*4*D*D
    short* wt_ff1  = wt_qkvo + (size_t)L * 4 * D * D;  // L*D*F
    short* wt_ff2  = wt_ff1  + (size_t)L * D * F;      // L*F*D
    short* wt_in   = wt_ff2  + (size_t)L * F * D;      // D*IN

    const size_t CZ = (size_t)B * H * S * DK;       // == HSZ
    short* qb = qkv_bf;
    short* kb = qkv_bf + CZ;
    short* vt = qkv_bf + 2 * CZ;                    // V^T written directly by qkv GEMM
    short* ctx_bf = qkv_bf + 3 * CZ;
    short* ff1_bf = qkv_bf;                         // alias (qkv dead after Wo)

    dim3 blk(256);

    // --- prologue: pe, input cvt, ALL weight transposes (hoisted) ---
    pe_kernel<<<dim3(S), blk, 0, stream>>>(rel_emb, pe);
    cvt_kernel<<<dim3(BS * IN / 1024), blk, 0, stream>>>(x, xb);
    wtrans_kernel<<<dim3(D / 32, IN / 32, 1), blk, 0, stream>>>(in_W, wt_in, IN, D);
    wtrans_kernel<<<dim3(D / 32, D / 32, 4 * L), blk, 0, stream>>>(qkvo_W, wt_qkvo, D, D);
    wtrans_kernel<<<dim3(F / 32, D / 32, L), blk, 0, stream>>>(ff_W1, wt_ff1, D, F);
    wtrans_kernel<<<dim3(D / 32, F / 32, L), blk, 0, stream>>>(ff_W2, wt_ff2, F, D);

    // h = x @ in_W + in_b + pe   (bf16)
    mfma_gemm<<<dim3(D / 128, BS / 128, 1), blk, 0, stream>>>(
        xb, wt_in, in_b, h_bf, BS, D, IN, IN, IN, 2, pe, 0, 0, 0);

    for (int l = 0; l < L; ++l) {
        const float* bl = qkvo_b + (size_t)l * 4 * D;
        // q,k,v projections; V scattered directly as V^T (no vtrans kernel)
        mfma_gemm<<<dim3(D / 128, BS / 128, 3), blk, 0, stream>>>(
            h_bf, wt_qkvo + (size_t)l * 4 * D * D, bl, qkv_bf,
            BS, D, D, D, D, 3, nullptr, (long)D * D, (long)D, (long)CZ);
        attn_mfma<<<dim3(S / 64, B * H), blk, 0, stream>>>(qb, kb, vt, ctx_bf);
        // tmp = ctx @ W_o + b_o   (128x64 tiles, 512 blocks)
        mfma_gemm_n64<<<dim3(D / 64, BS / 128), blk, 0, stream>>>(
            ctx_bf, wt_qkvo + (size_t)(l * 4 + 3) * D * D, bl + 3 * D, tmp_bf,
            BS, D, D, D, D, 0);
        // h1 = LN(h + tmp)
        ln_kernel<<<dim3(BS), dim3(128), 0, stream>>>(
            h_bf, tmp_bf, ln_g + (size_t)l * 2 * D, ln_bb + (size_t)l * 2 * D, h1_bf);
        // ff1 = relu(h1 @ W1 + b1)
        mfma_gemm<<<dim3(F / 128, BS / 128, 1), blk, 0, stream>>>(
            h1_bf, wt_ff1 + (size_t)l * D * F, ff_b1 + (size_t)l * F, ff1_bf,
            BS, F, D, D, D, 1, nullptr, 0, 0, 0);
        // tmp = ff1 @ W2 + b2   (128x64 tiles, K=2048 full, 512 blocks)
        mfma_gemm_n64<<<dim3(D / 64, BS / 128), blk, 0, stream>>>(
            ff1_bf, wt_ff2 + (size_t)l * F * D, ff_b2 + (size_t)l * D, tmp_bf,
            BS, D, F, F, F, 0);
        // h = LN(h1 + tmp)
        ln_kernel<<<dim3(BS), dim3(128), 0, stream>>>(
            h1_bf, tmp_bf, ln_g + (size_t)l * 2 * D + D, ln_bb + (size_t)l * 2 * D + D,
            h_bf);
    }

    out_kernel<<<dim3(BS / 4), blk, 0, stream>>>(h_bf, out_W, out_b, out);
}